// Round 2
// baseline (112.921 us; speedup 1.0000x reference)
//
#include <hip/hip_runtime.h>
#include <hip/hip_bf16.h>

// JPEG 8x8 block DCT + quantization.
// image: [16,1,1024,1024] fp32; quality_factor: [16] fp32
// out:   [16,64,128,128] fp32, channel = k*8+l, out = (C @ (blk-128) @ C^T) / (factor*Q)
//
// R2 changes vs R1:
//  - constexpr coefficient tables (fold to immediates; removes all constant-memory
//    s_load traffic from the inner loops — theory for the 111us and the only
//    module-level device state in R1)
//  - row-streaming stage 1: load one pixel row, accumulate into tmp[k][m] on the
//    fly -> live regs ~100 instead of ~170, compute overlaps loads

#define BS 8
#define HPIX 1024
#define WPIX 1024
#define HB (HPIX / BS)   // 128
#define WB (WPIX / BS)   // 128
#define BATCH 16

// Orthonormal DCT-II matrix C[k][n] = f_k * cos(pi*(2n+1)*k/16), fp32-rounded.
constexpr float DCT[8][8] = {
  { 0.35355339059327373f,  0.35355339059327373f,  0.35355339059327373f,  0.35355339059327373f,
    0.35355339059327373f,  0.35355339059327373f,  0.35355339059327373f,  0.35355339059327373f },
  { 0.49039264020161522f,  0.41573480615127262f,  0.27778511650980114f,  0.09754516100806413f,
   -0.09754516100806413f, -0.27778511650980114f, -0.41573480615127262f, -0.49039264020161522f },
  { 0.46193976625564337f,  0.19134171618254492f, -0.19134171618254492f, -0.46193976625564337f,
   -0.46193976625564337f, -0.19134171618254492f,  0.19134171618254492f,  0.46193976625564337f },
  { 0.41573480615127262f, -0.09754516100806413f, -0.49039264020161522f, -0.27778511650980114f,
    0.27778511650980114f,  0.49039264020161522f,  0.09754516100806413f, -0.41573480615127262f },
  { 0.35355339059327373f, -0.35355339059327373f, -0.35355339059327373f,  0.35355339059327373f,
    0.35355339059327373f, -0.35355339059327373f, -0.35355339059327373f,  0.35355339059327373f },
  { 0.27778511650980114f, -0.49039264020161522f,  0.09754516100806413f,  0.41573480615127262f,
   -0.41573480615127262f, -0.09754516100806413f,  0.49039264020161522f, -0.27778511650980114f },
  { 0.19134171618254492f, -0.46193976625564337f,  0.46193976625564337f, -0.19134171618254492f,
   -0.19134171618254492f,  0.46193976625564337f, -0.46193976625564337f,  0.19134171618254492f },
  { 0.09754516100806413f, -0.27778511650980114f,  0.41573480615127262f, -0.49039264020161522f,
    0.49039264020161522f, -0.41573480615127262f,  0.27778511650980114f, -0.09754516100806413f },
};

// 1 / (LUMINANCE_QUANTIZATION_TABLE / 100) = 100 / table entry
constexpr float INVQ[8][8] = {
  { 6.25f,              9.09090909090909f,  10.0f,              6.25f,
    4.16666666666667f,  2.5f,               1.96078431372549f,  1.63934426229508f },
  { 8.33333333333333f,  8.33333333333333f,  7.14285714285714f,  5.26315789473684f,
    3.84615384615385f,  1.72413793103448f,  1.66666666666667f,  1.81818181818182f },
  { 7.14285714285714f,  7.69230769230769f,  6.25f,              4.16666666666667f,
    2.5f,               1.75438596491228f,  1.44927536231884f,  1.78571428571429f },
  { 7.14285714285714f,  5.88235294117647f,  4.54545454545455f,  3.44827586206897f,
    1.96078431372549f,  1.14942528735632f,  1.25f,              1.61290322580645f },
  { 5.55555555555556f,  4.54545454545455f,  2.70270270270270f,  1.78571428571429f,
    1.47058823529412f,  0.91743119266055f,  0.970873786407767f, 1.29870129870130f },
  { 4.16666666666667f,  2.77777777777778f,  1.81818181818182f,  1.5625f,
    1.23456790123457f,  0.961538461538462f, 0.884955752212389f, 1.08695652173913f },
  { 2.04081632653061f,  1.5625f,            1.28205128205128f,  1.14942528735632f,
    0.970873786407767f, 0.826446280991736f, 0.833333333333333f, 0.990099009900990f },
  { 1.38888888888889f,  1.08695652173913f,  1.05263157894737f,  1.02040816326531f,
    0.892857142857143f, 1.0f,               0.970873786407767f, 1.01010101010101f },
};

__global__ __launch_bounds__(256) void jpeg_dct_q_kernel(
    const float* __restrict__ img,
    const float* __restrict__ qf,
    float* __restrict__ out)
{
    const int tid = blockIdx.x * blockDim.x + threadIdx.x;
    const int w = tid & (WB - 1);          // block col (consecutive across lanes -> coalesced)
    const int h = (tid >> 7) & (HB - 1);   // block row
    const int b = tid >> 14;               // batch

    const float* rowbase = img + ((size_t)b << 20) + (size_t)(h * BS) * WPIX + (size_t)(w * BS);

    // Stage 1 (row-streaming): tmp[k][m] = sum_n DCT[k][n] * (pix[n][m] - 128)
    float tmp[8][8];
#pragma unroll
    for (int k = 0; k < 8; ++k)
#pragma unroll
        for (int m = 0; m < 8; ++m)
            tmp[k][m] = 0.0f;

#pragma unroll
    for (int n = 0; n < 8; ++n) {
        const float4* p = reinterpret_cast<const float4*>(rowbase + n * WPIX);
        float4 a = p[0];
        float4 c = p[1];
        float r[8];
        r[0] = a.x - 128.0f; r[1] = a.y - 128.0f; r[2] = a.z - 128.0f; r[3] = a.w - 128.0f;
        r[4] = c.x - 128.0f; r[5] = c.y - 128.0f; r[6] = c.z - 128.0f; r[7] = c.w - 128.0f;
#pragma unroll
        for (int k = 0; k < 8; ++k) {
            const float cf = DCT[k][n];   // constexpr -> immediate, no memory access
#pragma unroll
            for (int m = 0; m < 8; ++m)
                tmp[k][m] = fmaf(cf, r[m], tmp[k][m]);
        }
    }

    // Quantization scale: factor = QF<50 ? 5000/QF : 200-2*QF
    const float q = qf[b];
    const float factor = (q < 50.0f) ? (5000.0f / q) : (200.0f - 2.0f * q);
    const float rf = 1.0f / factor;

    // Stage 2: out[k][l] = (sum_m DCT[l][m] * tmp[k][m]) * rf * INVQ[k][l]
    float* obase = out + ((size_t)b << 20) + (size_t)h * WB + (size_t)w;
#pragma unroll
    for (int k = 0; k < 8; ++k) {
#pragma unroll
        for (int l = 0; l < 8; ++l) {
            float s = 0.0f;
#pragma unroll
            for (int m = 0; m < 8; ++m)
                s = fmaf(DCT[l][m], tmp[k][m], s);
            s = s * rf * INVQ[k][l];
            obase[(size_t)(k * 8 + l) * (HB * WB)] = s;
        }
    }
}

extern "C" void kernel_launch(void* const* d_in, const int* in_sizes, int n_in,
                              void* d_out, int out_size, void* d_ws, size_t ws_size,
                              hipStream_t stream) {
    const float* img = (const float*)d_in[0];
    const float* qf  = (const float*)d_in[1];
    float* out = (float*)d_out;

    const int total_blocks = BATCH * HB * WB;   // 262144 threads, one per 8x8 block
    const int block = 256;
    const int grid = total_blocks / block;      // 1024

    jpeg_dct_q_kernel<<<grid, block, 0, stream>>>(img, qf, out);
}

// Round 3
// 111.283 us; speedup vs baseline: 1.0147x; 1.0147x over previous
//
#include <hip/hip_runtime.h>
#include <hip/hip_bf16.h>

// JPEG 8x8 block DCT + quantization.
// image: [16,1,1024,1024] fp32; quality_factor: [16] fp32
// out:   [16,64,128,128] fp32, channel = k*8+l, out = (C @ (blk-128) @ C^T) / (factor*Q)
//
// R3 changes vs R2 (kernel dispatch was 41.6us, ~1.2cyc/VMEM-instr => VMEM-issue bound
// on 64 dword stores/thread; VGPR=48 showed compiler rematerialized pixel loads):
//  - __launch_bounds__(256, 4): 128-VGPR cap, enough to keep tmp[8][8] live (no remat)
//  - LDS ping-pong transpose epilogue: per DCT row k, stage 8 channels in LDS, flush
//    with float4 stores (2/thread/k). VMEM: 16 ld + 64 st -> 16 ld + 16 st per thread.

#define BS 8
#define HPIX 1024
#define WPIX 1024
#define HB (HPIX / BS)   // 128
#define WB (WPIX / BS)   // 128
#define BATCH 16

// Orthonormal DCT-II matrix C[k][n] = f_k * cos(pi*(2n+1)*k/16), fp32-rounded.
constexpr float DCT[8][8] = {
  { 0.35355339059327373f,  0.35355339059327373f,  0.35355339059327373f,  0.35355339059327373f,
    0.35355339059327373f,  0.35355339059327373f,  0.35355339059327373f,  0.35355339059327373f },
  { 0.49039264020161522f,  0.41573480615127262f,  0.27778511650980114f,  0.09754516100806413f,
   -0.09754516100806413f, -0.27778511650980114f, -0.41573480615127262f, -0.49039264020161522f },
  { 0.46193976625564337f,  0.19134171618254492f, -0.19134171618254492f, -0.46193976625564337f,
   -0.46193976625564337f, -0.19134171618254492f,  0.19134171618254492f,  0.46193976625564337f },
  { 0.41573480615127262f, -0.09754516100806413f, -0.49039264020161522f, -0.27778511650980114f,
    0.27778511650980114f,  0.49039264020161522f,  0.09754516100806413f, -0.41573480615127262f },
  { 0.35355339059327373f, -0.35355339059327373f, -0.35355339059327373f,  0.35355339059327373f,
    0.35355339059327373f, -0.35355339059327373f, -0.35355339059327373f,  0.35355339059327373f },
  { 0.27778511650980114f, -0.49039264020161522f,  0.09754516100806413f,  0.41573480615127262f,
   -0.41573480615127262f, -0.09754516100806413f,  0.49039264020161522f, -0.27778511650980114f },
  { 0.19134171618254492f, -0.46193976625564337f,  0.46193976625564337f, -0.19134171618254492f,
   -0.19134171618254492f,  0.46193976625564337f, -0.46193976625564337f,  0.19134171618254492f },
  { 0.09754516100806413f, -0.27778511650980114f,  0.41573480615127262f, -0.49039264020161522f,
    0.49039264020161522f, -0.41573480615127262f,  0.27778511650980114f, -0.09754516100806413f },
};

// 1 / (LUMINANCE_QUANTIZATION_TABLE / 100) = 100 / table entry
constexpr float INVQ[8][8] = {
  { 6.25f,              9.09090909090909f,  10.0f,              6.25f,
    4.16666666666667f,  2.5f,               1.96078431372549f,  1.63934426229508f },
  { 8.33333333333333f,  8.33333333333333f,  7.14285714285714f,  5.26315789473684f,
    3.84615384615385f,  1.72413793103448f,  1.66666666666667f,  1.81818181818182f },
  { 7.14285714285714f,  7.69230769230769f,  6.25f,              4.16666666666667f,
    2.5f,               1.75438596491228f,  1.44927536231884f,  1.78571428571429f },
  { 7.14285714285714f,  5.88235294117647f,  4.54545454545455f,  3.44827586206897f,
    1.96078431372549f,  1.14942528735632f,  1.25f,              1.61290322580645f },
  { 5.55555555555556f,  4.54545454545455f,  2.70270270270270f,  1.78571428571429f,
    1.47058823529412f,  0.91743119266055f,  0.970873786407767f, 1.29870129870130f },
  { 4.16666666666667f,  2.77777777777778f,  1.81818181818182f,  1.5625f,
    1.23456790123457f,  0.961538461538462f, 0.884955752212389f, 1.08695652173913f },
  { 2.04081632653061f,  1.5625f,            1.28205128205128f,  1.14942528735632f,
    0.970873786407767f, 0.826446280991736f, 0.833333333333333f, 0.990099009900990f },
  { 1.38888888888889f,  1.08695652173913f,  1.05263157894737f,  1.02040816326531f,
    0.892857142857143f, 1.0f,               0.970873786407767f, 1.01010101010101f },
};

// WG = 256 threads = 2 consecutive block-rows (h0, h0+1) x 128 block-cols, one batch.
// Thread t: w = t&127, hsub = t>>7. Grid = 16 batches * 64 h-pairs = 1024 WGs.
__global__ __launch_bounds__(256, 4) void jpeg_dct_q_kernel(
    const float* __restrict__ img,
    const float* __restrict__ qf,
    float* __restrict__ out)
{
    // ping-pong staging: [buf][hsub][l][w]; 2*2*8*128*4B = 16 KB
    __shared__ float lds[2][2][8][WB];

    const int t = threadIdx.x;
    const int g = blockIdx.x;
    const int b = g >> 6;                 // batch
    const int h0 = (g & 63) << 1;         // first block-row of the pair
    const int w = t & (WB - 1);           // block col
    const int hsub = t >> 7;              // 0/1 within the pair
    const int h = h0 + hsub;

    const float* rowbase = img + ((size_t)b << 20) + (size_t)(h * BS) * WPIX + (size_t)(w * BS);

    // Stage 1 (row-streaming): tmp[k][m] = sum_n DCT[k][n] * (pix[n][m] - 128)
    float tmp[8][8];
#pragma unroll
    for (int k = 0; k < 8; ++k)
#pragma unroll
        for (int m = 0; m < 8; ++m)
            tmp[k][m] = 0.0f;

#pragma unroll
    for (int n = 0; n < 8; ++n) {
        const float4* p = reinterpret_cast<const float4*>(rowbase + n * WPIX);
        float4 a = p[0];
        float4 c = p[1];
        float r[8];
        r[0] = a.x - 128.0f; r[1] = a.y - 128.0f; r[2] = a.z - 128.0f; r[3] = a.w - 128.0f;
        r[4] = c.x - 128.0f; r[5] = c.y - 128.0f; r[6] = c.z - 128.0f; r[7] = c.w - 128.0f;
#pragma unroll
        for (int k = 0; k < 8; ++k) {
            const float cf = DCT[k][n];   // constexpr -> immediate
#pragma unroll
            for (int m = 0; m < 8; ++m)
                tmp[k][m] = fmaf(cf, r[m], tmp[k][m]);
        }
    }

    // Quantization scale: factor = QF<50 ? 5000/QF : 200-2*QF
    const float q = qf[b];
    const float factor = (q < 50.0f) ? (5000.0f / q) : (200.0f - 2.0f * q);
    const float rf = 1.0f / factor;

    // Phase-2 (flush) thread mapping: thread t -> (p_hsub, p_l, 2 w-groups of 4)
    const int p_hsub = t >> 7;
    const int p_l = (t >> 4) & 7;
    const int p_g0 = t & 15;
    const size_t obatch = (size_t)b << 20;

    // Per DCT row k: compute 8 channels -> LDS (ping-pong) -> float4 stores.
    // One barrier per k is sufficient: reads of buf at k precede the barrier at
    // k+1, which precedes the next write of that buf at k+2.
#pragma unroll
    for (int k = 0; k < 8; ++k) {
        const int buf = k & 1;
#pragma unroll
        for (int l = 0; l < 8; ++l) {
            float s = 0.0f;
#pragma unroll
            for (int m = 0; m < 8; ++m)
                s = fmaf(DCT[l][m], tmp[k][m], s);
            lds[buf][hsub][l][w] = s * rf * INVQ[k][l];
        }
        __syncthreads();
#pragma unroll
        for (int it = 0; it < 2; ++it) {
            const int grp = p_g0 + 16 * it;          // w-group: 4 consecutive w
            float4 v = *reinterpret_cast<const float4*>(&lds[buf][p_hsub][p_l][4 * grp]);
            float* dst = out + obatch + (size_t)(k * 8 + p_l) * (HB * WB)
                             + (size_t)(h0 + p_hsub) * WB + 4 * grp;
            *reinterpret_cast<float4*>(dst) = v;
        }
    }
}

extern "C" void kernel_launch(void* const* d_in, const int* in_sizes, int n_in,
                              void* d_out, int out_size, void* d_ws, size_t ws_size,
                              hipStream_t stream) {
    const float* img = (const float*)d_in[0];
    const float* qf  = (const float*)d_in[1];
    float* out = (float*)d_out;

    const int grid = BATCH * (HB / 2);   // 1024 WGs: one per (batch, block-row pair)
    const int block = 256;

    jpeg_dct_q_kernel<<<grid, block, 0, stream>>>(img, qf, out);
}